// Round 1
// baseline (2847.963 us; speedup 1.0000x reference)
//
#include <hip/hip_runtime.h>
#include <math.h>

#define D 128
#define THREADS 256

// ---------------------------------------------------------------------------
// Phase 1: in-degree count (int atomics, exact)
// ---------------------------------------------------------------------------
__global__ __launch_bounds__(THREADS) void k_deg(const int* __restrict__ dst,
                                                 int* __restrict__ deg, int E) {
    int i = blockIdx.x * THREADS + threadIdx.x;
    if (i < E) atomicAdd(&deg[dst[i]], 1);
}

// ---------------------------------------------------------------------------
// Phase 2: norm = rsqrt(max(deg,1)) in place (deg/normf alias the same ws)
// ---------------------------------------------------------------------------
__global__ __launch_bounds__(THREADS) void k_norm(const int* degc, float* normf, int n) {
    int i = blockIdx.x * THREADS + threadIdx.x;
    if (i < n) {
        float d = (float)degc[i];
        normf[i] = rsqrtf(fmaxf(d, 1.0f));
    }
}

// ---------------------------------------------------------------------------
// Phase 3: agg[dst] += features[src] * norm[src]
// 32 lanes per edge, float4 per lane -> one coalesced 512B row gather,
// 4 native fp32 atomic adds per lane.
// ---------------------------------------------------------------------------
__global__ __launch_bounds__(THREADS) void k_scatter(
    const float* __restrict__ features, const int* __restrict__ src,
    const int* __restrict__ dst, const float* __restrict__ norm,
    float* __restrict__ agg, int E) {
    int gtid = blockIdx.x * THREADS + threadIdx.x;
    int e = gtid >> 5;
    if (e >= E) return;
    int lane = gtid & 31;
    int s = src[e];
    int d = dst[e];
    float ns = norm[s];
    float4 f = ((const float4*)(features + (size_t)s * D))[lane];
    float* a = agg + (size_t)d * D + lane * 4;
    unsafeAtomicAdd(a + 0, f.x * ns);
    unsafeAtomicAdd(a + 1, f.y * ns);
    unsafeAtomicAdd(a + 2, f.z * ns);
    unsafeAtomicAdd(a + 3, f.w * ns);
}

// ---------------------------------------------------------------------------
// Phase 4: t = 0.9*agg*norm + 0.1*init ; out = relu(0.5*t + 0.5*(t @ W^T))
// agg is read from `out` and overwritten in place (read->barrier->write per
// 32-node group, per block; groups are disjoint across blocks).
// LDS: Wt[k][j] = W[j][k] (64KB, row-reads bank-spread) + T[k][n] (16KB).
// Total exactly 81920B -> 2 blocks/CU. 4 nodes x 4 cols per thread.
// ---------------------------------------------------------------------------
__global__ __launch_bounds__(THREADS, 2) void k_final(
    const float* __restrict__ initf, const float* __restrict__ W,
    const float* __restrict__ norm, float* __restrict__ out, int n) {
    __shared__ float Wt[D * D];   // [k][j]
    __shared__ float T[D * 32];   // [k][node-in-group]
    const int tid = threadIdx.x;

    // One-time W transpose stage (32-way write conflicts, ~4K clk, amortized
    // over ~6 node-groups per block).
    for (int i = tid; i < D * D; i += THREADS) {
        int j = i >> 7, k = i & (D - 1);
        Wt[k * D + j] = W[i];
    }

    const int jv = tid & 31;       // column-quad index
    const int ng = tid >> 5;       // node-quad index
    const int j0 = jv * 4;
    const int n0 = ng * 4;
    const int sn = tid >> 3;       // staging: node 0..31
    const int sv0 = (tid & 7) * 4; // staging: float4 index base 0..28

    const int numGroups = (n + 31) >> 5;
    for (int g = blockIdx.x; g < numGroups; g += gridDim.x) {
        const int base = g << 5;
        __syncthreads();  // protect T from previous iteration's readers
        {
            const int node = base + sn;
            if (node < n) {
                const float nm = norm[node];
                const float4* ag = (const float4*)(out + (size_t)node * D);
                const float4* iv = (const float4*)(initf + (size_t)node * D);
#pragma unroll
                for (int q = 0; q < 4; ++q) {
                    const int v4 = sv0 + q;
                    float4 a4 = ag[v4];
                    float4 i4 = iv[v4];
                    const int k = v4 * 4;
                    T[(k + 0) * 32 + sn] = 0.9f * (a4.x * nm) + 0.1f * i4.x;
                    T[(k + 1) * 32 + sn] = 0.9f * (a4.y * nm) + 0.1f * i4.y;
                    T[(k + 2) * 32 + sn] = 0.9f * (a4.z * nm) + 0.1f * i4.z;
                    T[(k + 3) * 32 + sn] = 0.9f * (a4.w * nm) + 0.1f * i4.w;
                }
            } else {
#pragma unroll
                for (int q = 0; q < 4; ++q) {
                    const int k = (sv0 + q) * 4;
                    T[(k + 0) * 32 + sn] = 0.0f;
                    T[(k + 1) * 32 + sn] = 0.0f;
                    T[(k + 2) * 32 + sn] = 0.0f;
                    T[(k + 3) * 32 + sn] = 0.0f;
                }
            }
        }
        __syncthreads();

        float acc[4][4];
#pragma unroll
        for (int a = 0; a < 4; ++a)
#pragma unroll
            for (int b = 0; b < 4; ++b) acc[a][b] = 0.0f;

#pragma unroll 8
        for (int k = 0; k < D; ++k) {
            const float4 t4 = *(const float4*)&T[k * 32 + n0];
            const float4 w4 = *(const float4*)&Wt[k * D + j0];
            acc[0][0] += t4.x * w4.x; acc[0][1] += t4.x * w4.y;
            acc[0][2] += t4.x * w4.z; acc[0][3] += t4.x * w4.w;
            acc[1][0] += t4.y * w4.x; acc[1][1] += t4.y * w4.y;
            acc[1][2] += t4.y * w4.z; acc[1][3] += t4.y * w4.w;
            acc[2][0] += t4.z * w4.x; acc[2][1] += t4.z * w4.y;
            acc[2][2] += t4.z * w4.z; acc[2][3] += t4.z * w4.w;
            acc[3][0] += t4.w * w4.x; acc[3][1] += t4.w * w4.y;
            acc[3][2] += t4.w * w4.z; acc[3][3] += t4.w * w4.w;
        }

#pragma unroll
        for (int a = 0; a < 4; ++a) {
            const int node = base + n0 + a;
            if (node < n) {
                const float t0 = T[(j0 + 0) * 32 + n0 + a];
                const float t1 = T[(j0 + 1) * 32 + n0 + a];
                const float t2 = T[(j0 + 2) * 32 + n0 + a];
                const float t3 = T[(j0 + 3) * 32 + n0 + a];
                float4 r;
                r.x = fmaxf(0.5f * t0 + 0.5f * acc[a][0], 0.0f);
                r.y = fmaxf(0.5f * t1 + 0.5f * acc[a][1], 0.0f);
                r.z = fmaxf(0.5f * t2 + 0.5f * acc[a][2], 0.0f);
                r.w = fmaxf(0.5f * t3 + 0.5f * acc[a][3], 0.0f);
                *(float4*)(out + (size_t)node * D + j0) = r;
            }
        }
    }
}

// ---------------------------------------------------------------------------
extern "C" void kernel_launch(void* const* d_in, const int* in_sizes, int n_in,
                              void* d_out, int out_size, void* d_ws, size_t ws_size,
                              hipStream_t stream) {
    const float* features = (const float*)d_in[0];
    const float* initf    = (const float*)d_in[1];
    const float* W        = (const float*)d_in[2];
    const int*   src      = (const int*)d_in[3];
    const int*   dst      = (const int*)d_in[4];
    float* out = (float*)d_out;

    const int n = in_sizes[0] / D;
    const int E = in_sizes[3];
    if (n <= 0) return;

    int*   deg   = (int*)d_ws;    // n ints
    float* normf = (float*)d_ws;  // aliases deg after k_norm

    // zero deg counters and the agg accumulator (= d_out)
    hipMemsetAsync(d_ws, 0, (size_t)n * sizeof(int), stream);
    hipMemsetAsync(d_out, 0, (size_t)n * D * sizeof(float), stream);

    k_deg<<<(E + THREADS - 1) / THREADS, THREADS, 0, stream>>>(dst, deg, E);
    k_norm<<<(n + THREADS - 1) / THREADS, THREADS, 0, stream>>>(deg, normf, n);

    const int sc_total = E * 32;  // 51.2M threads, 32 lanes/edge
    k_scatter<<<(sc_total + THREADS - 1) / THREADS, THREADS, 0, stream>>>(
        features, src, dst, normf, out, E);

    k_final<<<512, THREADS, 0, stream>>>(initf, W, normf, out, n);
}

// Round 2
// 410.173 us; speedup vs baseline: 6.9433x; 6.9433x over previous
//
#include <hip/hip_runtime.h>
#include <math.h>

#define D 128
#define THREADS 256

// ---------------------------------------------------------------------------
// Phase 1: in-degree count (int atomics, 1.6M ops)
// ---------------------------------------------------------------------------
__global__ __launch_bounds__(THREADS) void k_deg(const int* __restrict__ dst,
                                                 int* __restrict__ deg, int E) {
    int i = blockIdx.x * THREADS + threadIdx.x;
    if (i < E) atomicAdd(&deg[dst[i]], 1);
}

// ---------------------------------------------------------------------------
// Phase 2a: per-block sums of deg (for the two-level exclusive scan)
// ---------------------------------------------------------------------------
__global__ __launch_bounds__(THREADS) void k_bsum(const int* __restrict__ deg,
                                                  int* __restrict__ bsum, int n) {
    __shared__ int sh[THREADS];
    const int tid = threadIdx.x;
    int i = blockIdx.x * THREADS + tid;
    sh[tid] = (i < n) ? deg[i] : 0;
    __syncthreads();
    for (int s = THREADS / 2; s > 0; s >>= 1) {
        if (tid < s) sh[tid] += sh[tid + s];
        __syncthreads();
    }
    if (tid == 0) bsum[blockIdx.x] = sh[0];
}

// ---------------------------------------------------------------------------
// Phase 2b: exclusive scan of block sums (single block, nb <= 512)
// ---------------------------------------------------------------------------
__global__ __launch_bounds__(512) void k_scan_bsum(int* __restrict__ bsum, int nb) {
    __shared__ int sh[512];
    const int tid = threadIdx.x;
    int v = (tid < nb) ? bsum[tid] : 0;
    sh[tid] = v;
    __syncthreads();
    for (int s = 1; s < 512; s <<= 1) {
        int t = (tid >= s) ? sh[tid - s] : 0;
        __syncthreads();
        sh[tid] += t;
        __syncthreads();
    }
    if (tid < nb) bsum[tid] = sh[tid] - v;  // exclusive
}

// ---------------------------------------------------------------------------
// Phase 2c: per-block exclusive rescan + base -> off[] and cursor[]
// ---------------------------------------------------------------------------
__global__ __launch_bounds__(THREADS) void k_scan_final(
    const int* __restrict__ deg, const int* __restrict__ bsum,
    int* __restrict__ off, int* __restrict__ cursor, int n) {
    __shared__ int sh[THREADS];
    const int tid = threadIdx.x;
    int i = blockIdx.x * THREADS + tid;
    int v = (i < n) ? deg[i] : 0;
    sh[tid] = v;
    __syncthreads();
    for (int s = 1; s < THREADS; s <<= 1) {
        int t = (tid >= s) ? sh[tid - s] : 0;
        __syncthreads();
        sh[tid] += t;
        __syncthreads();
    }
    if (i < n) {
        int excl = sh[tid] - v + bsum[blockIdx.x];
        off[i] = excl;
        cursor[i] = excl;
        if (i == n - 1) off[n] = excl + v;  // off[n] = E
    }
}

// ---------------------------------------------------------------------------
// Phase 3: norm = rsqrt(max(deg,1))
// ---------------------------------------------------------------------------
__global__ __launch_bounds__(THREADS) void k_norm(const int* __restrict__ degc,
                                                  float* __restrict__ normf, int n) {
    int i = blockIdx.x * THREADS + threadIdx.x;
    if (i < n) normf[i] = rsqrtf(fmaxf((float)degc[i], 1.0f));
}

// ---------------------------------------------------------------------------
// Phase 4: CSR placement — csr_src[cursor[dst]++] = src  (1.6M int atomics)
// ---------------------------------------------------------------------------
__global__ __launch_bounds__(THREADS) void k_place(
    const int* __restrict__ src, const int* __restrict__ dst,
    int* __restrict__ cursor, int* __restrict__ csr, int E) {
    int e = blockIdx.x * THREADS + threadIdx.x;
    if (e < E) {
        int p = atomicAdd(&cursor[dst[e]], 1);
        csr[p] = src[e];
    }
}

// ---------------------------------------------------------------------------
// Phase 5: gather-aggregate. 32 lanes per node, float4/lane: for each
// neighbor, one coalesced 512B row read + fma; single row write of
// t = 0.9*agg*norm + 0.1*init. Zero fp32 atomics.
// ---------------------------------------------------------------------------
__global__ __launch_bounds__(THREADS) void k_agg(
    const float* __restrict__ features, const float* __restrict__ initf,
    const int* __restrict__ off, const int* __restrict__ csr,
    const float* __restrict__ normf, float* __restrict__ out, int n) {
    int g = (blockIdx.x * THREADS + threadIdx.x) >> 5;
    if (g >= n) return;
    const int lane = threadIdx.x & 31;
    const int begin = off[g];
    const int end = off[g + 1];

    float4 acc = {0.f, 0.f, 0.f, 0.f};
    int j = begin;
    // 2-deep unroll to keep two row-gathers in flight
    for (; j + 2 <= end; j += 2) {
        int s0 = csr[j], s1 = csr[j + 1];
        float w0 = normf[s0], w1 = normf[s1];
        float4 f0 = ((const float4*)(features + (size_t)s0 * D))[lane];
        float4 f1 = ((const float4*)(features + (size_t)s1 * D))[lane];
        acc.x += f0.x * w0; acc.y += f0.y * w0; acc.z += f0.z * w0; acc.w += f0.w * w0;
        acc.x += f1.x * w1; acc.y += f1.y * w1; acc.z += f1.z * w1; acc.w += f1.w * w1;
    }
    if (j < end) {
        int s0 = csr[j];
        float w0 = normf[s0];
        float4 f0 = ((const float4*)(features + (size_t)s0 * D))[lane];
        acc.x += f0.x * w0; acc.y += f0.y * w0; acc.z += f0.z * w0; acc.w += f0.w * w0;
    }

    const float nv = normf[g];
    float4 iv = ((const float4*)(initf + (size_t)g * D))[lane];
    float4 t;
    t.x = 0.9f * (acc.x * nv) + 0.1f * iv.x;
    t.y = 0.9f * (acc.y * nv) + 0.1f * iv.y;
    t.z = 0.9f * (acc.z * nv) + 0.1f * iv.z;
    t.w = 0.9f * (acc.w * nv) + 0.1f * iv.w;
    ((float4*)(out + (size_t)g * D))[lane] = t;
}

// ---------------------------------------------------------------------------
// Phase 6: out = relu(0.5*t + 0.5*(t @ W^T)), t read from `out` in place.
// LDS: Wt[k][j] = W[j][k] (64KB) + T[k][n] (16KB) = 81920B -> 2 blocks/CU.
// ---------------------------------------------------------------------------
__global__ __launch_bounds__(THREADS, 2) void k_final(
    const float* __restrict__ W, float* __restrict__ out, int n) {
    __shared__ float Wt[D * D];   // [k][j]
    __shared__ float T[D * 32];   // [k][node-in-group]
    const int tid = threadIdx.x;

    for (int i = tid; i < D * D; i += THREADS) {
        int j = i >> 7, k = i & (D - 1);
        Wt[k * D + j] = W[i];
    }

    const int jv = tid & 31;       // column-quad index
    const int ng = tid >> 5;       // node-quad index
    const int j0 = jv * 4;
    const int n0 = ng * 4;
    const int sn = tid >> 3;       // staging: node 0..31
    const int sv0 = (tid & 7) * 4; // staging: float4 index base 0..28

    const int numGroups = (n + 31) >> 5;
    for (int g = blockIdx.x; g < numGroups; g += gridDim.x) {
        const int base = g << 5;
        __syncthreads();  // protect T from previous iteration's readers
        {
            const int node = base + sn;
            if (node < n) {
                const float4* tg = (const float4*)(out + (size_t)node * D);
#pragma unroll
                for (int q = 0; q < 4; ++q) {
                    const int v4 = sv0 + q;
                    float4 a4 = tg[v4];
                    const int k = v4 * 4;
                    T[(k + 0) * 32 + sn] = a4.x;
                    T[(k + 1) * 32 + sn] = a4.y;
                    T[(k + 2) * 32 + sn] = a4.z;
                    T[(k + 3) * 32 + sn] = a4.w;
                }
            } else {
#pragma unroll
                for (int q = 0; q < 4; ++q) {
                    const int k = (sv0 + q) * 4;
                    T[(k + 0) * 32 + sn] = 0.0f;
                    T[(k + 1) * 32 + sn] = 0.0f;
                    T[(k + 2) * 32 + sn] = 0.0f;
                    T[(k + 3) * 32 + sn] = 0.0f;
                }
            }
        }
        __syncthreads();

        float acc[4][4];
#pragma unroll
        for (int a = 0; a < 4; ++a)
#pragma unroll
            for (int b = 0; b < 4; ++b) acc[a][b] = 0.0f;

#pragma unroll 8
        for (int k = 0; k < D; ++k) {
            const float4 t4 = *(const float4*)&T[k * 32 + n0];
            const float4 w4 = *(const float4*)&Wt[k * D + j0];
            acc[0][0] += t4.x * w4.x; acc[0][1] += t4.x * w4.y;
            acc[0][2] += t4.x * w4.z; acc[0][3] += t4.x * w4.w;
            acc[1][0] += t4.y * w4.x; acc[1][1] += t4.y * w4.y;
            acc[1][2] += t4.y * w4.z; acc[1][3] += t4.y * w4.w;
            acc[2][0] += t4.z * w4.x; acc[2][1] += t4.z * w4.y;
            acc[2][2] += t4.z * w4.z; acc[2][3] += t4.z * w4.w;
            acc[3][0] += t4.w * w4.x; acc[3][1] += t4.w * w4.y;
            acc[3][2] += t4.w * w4.z; acc[3][3] += t4.w * w4.w;
        }

#pragma unroll
        for (int a = 0; a < 4; ++a) {
            const int node = base + n0 + a;
            if (node < n) {
                const float t0 = T[(j0 + 0) * 32 + n0 + a];
                const float t1 = T[(j0 + 1) * 32 + n0 + a];
                const float t2 = T[(j0 + 2) * 32 + n0 + a];
                const float t3 = T[(j0 + 3) * 32 + n0 + a];
                float4 r;
                r.x = fmaxf(0.5f * t0 + 0.5f * acc[a][0], 0.0f);
                r.y = fmaxf(0.5f * t1 + 0.5f * acc[a][1], 0.0f);
                r.z = fmaxf(0.5f * t2 + 0.5f * acc[a][2], 0.0f);
                r.w = fmaxf(0.5f * t3 + 0.5f * acc[a][3], 0.0f);
                *(float4*)(out + (size_t)node * D + j0) = r;
            }
        }
    }
}

// ---------------------------------------------------------------------------
extern "C" void kernel_launch(void* const* d_in, const int* in_sizes, int n_in,
                              void* d_out, int out_size, void* d_ws, size_t ws_size,
                              hipStream_t stream) {
    const float* features = (const float*)d_in[0];
    const float* initf    = (const float*)d_in[1];
    const float* W        = (const float*)d_in[2];
    const int*   src      = (const int*)d_in[3];
    const int*   dst      = (const int*)d_in[4];
    float* out = (float*)d_out;

    const int n = in_sizes[0] / D;
    const int E = in_sizes[3];
    if (n <= 0) return;

    const int NB = (n + THREADS - 1) / THREADS;  // 391 for n=100000 (<=512)

    // workspace layout (all 4B-aligned)
    int*   deg    = (int*)d_ws;          // [n]
    int*   off    = deg + n;             // [n+1]
    int*   cursor = off + n + 1;         // [n]
    int*   bsum   = cursor + n;          // [512]
    float* normf  = (float*)(bsum + 512);// [n]
    int*   csr    = (int*)(normf + n);   // [E]

    hipMemsetAsync(deg, 0, (size_t)n * sizeof(int), stream);

    k_deg<<<(E + THREADS - 1) / THREADS, THREADS, 0, stream>>>(dst, deg, E);
    k_bsum<<<NB, THREADS, 0, stream>>>(deg, bsum, n);
    k_scan_bsum<<<1, 512, 0, stream>>>(bsum, NB);
    k_scan_final<<<NB, THREADS, 0, stream>>>(deg, bsum, off, cursor, n);
    k_norm<<<NB, THREADS, 0, stream>>>(deg, normf, n);
    k_place<<<(E + THREADS - 1) / THREADS, THREADS, 0, stream>>>(src, dst, cursor, csr, E);

    const int agg_total = n * 32;  // 32 lanes per node
    k_agg<<<(agg_total + THREADS - 1) / THREADS, THREADS, 0, stream>>>(
        features, initf, off, csr, normf, out, n);

    k_final<<<512, THREADS, 0, stream>>>(W, out, n);
}